// Round 5
// baseline (315.310 us; speedup 1.0000x reference)
//
#include <hip/hip_runtime.h>
#include <math.h>

#define SIZE_N 100000
#define B_TOTAL 131072
#define D 128
#define K 64
#define NNEG 5
#define TILE 16
#define BLOCK 256
#define WPB 4
#define NTILES (B_TOTAL / TILE)        // 8192
#define GRID_MAIN (NTILES / WPB)       // 2048
#define RTILES (SIZE_N / 16)           // 6250 row-tiles per table
#define GRID_PRE ((2 * RTILES) / WPB)  // 3125
#define QS 68                          // LDS fp32 word stride per pair row (2-way max conflicts)
#define CWS 136                        // fallback LDS stride

typedef short bf16x8 __attribute__((ext_vector_type(8)));
typedef float f32x4 __attribute__((ext_vector_type(4)));

union FragU { unsigned u[4]; bf16x8 v; };

// round-to-nearest-even fp32 -> bf16
__device__ __forceinline__ unsigned rne_hi(float x) {
    unsigned u = __float_as_uint(x);
    return (u + 0x7fffu + ((u >> 16) & 1u)) & 0xffff0000u;
}
__device__ __forceinline__ unsigned pkbf(float lo, float hi) {
    return (rne_hi(lo) >> 16) | rne_hi(hi);
}
__device__ __forceinline__ float bf2f(short s) {
    return __uint_as_float(((unsigned)(unsigned short)s) << 16);
}
__device__ __forceinline__ float log_sigmoid(float x) {
    return fminf(x, 0.f) - __logf(1.f + __expf(-fabsf(x)));
}

__global__ void zero_loss(float* out) { if (threadIdx.x == 0) out[0] = 0.f; }

// ---------- pass 1: NodeProj/CtxProj GEMMs + node bf16 table + cwb ----------
__global__ __launch_bounds__(BLOCK) void precompute(
    const float* __restrict__ node_emb, const float* __restrict__ ctx_emb,
    const float* __restrict__ comm_w,
    short* __restrict__ nodeb, short* __restrict__ nproj, short* __restrict__ cproj,
    short* __restrict__ cwb, float* __restrict__ out)
{
    __shared__ float qlds[WPB][16 * QS];
    const int tid = threadIdx.x;
    const int lane = tid & 63;
    const int wid = tid >> 6;
    const int i15 = lane & 15;
    const int g = lane >> 4;

    if (blockIdx.x == 0) {
        if (tid == 0) out[0] = 0.f;
#pragma unroll
        for (int t = 0; t < 4; ++t) {
            const int j = (tid * 4 + t) * 8;   // covers K*D = 8192
            float4 v0 = *(const float4*)(comm_w + j), v1 = *(const float4*)(comm_w + j + 4);
            FragU f;
            f.u[0] = pkbf(v0.x, v0.y); f.u[1] = pkbf(v0.z, v0.w);
            f.u[2] = pkbf(v1.x, v1.y); f.u[3] = pkbf(v1.z, v1.w);
            *(bf16x8*)(cwb + j) = f.v;
        }
    }

    const int tile = blockIdx.x * WPB + wid;       // 0..12499
    const bool isNode = tile < RTILES;
    const float* __restrict__ src = isNode ? node_emb : ctx_emb;
    const int r0 = (isNode ? tile : tile - RTILES) * 16;
    short* __restrict__ proj = isNode ? nproj : cproj;

    // B fragments from fp32 comm_w (L1/L2 hot)
    bf16x8 bfr[4][4];
#pragma unroll
    for (int ks = 0; ks < 4; ++ks)
#pragma unroll
        for (int nb = 0; nb < 4; ++nb) {
            const float* p = comm_w + (nb * 16 + i15) * D + ks * 32 + g * 8;
            float4 a = *(const float4*)p, b = *(const float4*)(p + 4);
            FragU f;
            f.u[0] = pkbf(a.x, a.y); f.u[1] = pkbf(a.z, a.w);
            f.u[2] = pkbf(b.x, b.y); f.u[3] = pkbf(b.z, b.w);
            bfr[ks][nb] = f.v;
        }

    const f32x4 z4 = {0.f, 0.f, 0.f, 0.f};
    f32x4 Acc[4] = {z4, z4, z4, z4};
    const float* __restrict__ arow = src + (size_t)(r0 + i15) * D + g * 8;
#pragma unroll
    for (int ks = 0; ks < 4; ++ks) {
        float4 a0 = *(const float4*)(arow + ks * 32), a1 = *(const float4*)(arow + ks * 32 + 4);
        FragU af;
        af.u[0] = pkbf(a0.x, a0.y); af.u[1] = pkbf(a0.z, a0.w);
        af.u[2] = pkbf(a1.x, a1.y); af.u[3] = pkbf(a1.z, a1.w);
        if (isNode) *(bf16x8*)(nodeb + (size_t)(r0 + i15) * D + ks * 32 + g * 8) = af.v;
#pragma unroll
        for (int nb = 0; nb < 4; ++nb)
            Acc[nb] = __builtin_amdgcn_mfma_f32_16x16x32_bf16(af.v, bfr[ks][nb], Acc[nb], 0, 0, 0);
    }

    // C layout (verified): Acc[nb][r] = P[row = g*4+r][col = i15+16nb]; transpose via per-wave LDS
#pragma unroll
    for (int nb = 0; nb < 4; ++nb)
#pragma unroll
        for (int r = 0; r < 4; ++r)
            qlds[wid][(g * 4 + r) * QS + i15 + 16 * nb] = Acc[nb][r];
    // read row i15, cols {8g..8g+7} and {32+8g..+7}; pack+store (full-line coverage per instr)
    const float* myrow = &qlds[wid][i15 * QS];
#pragma unroll
    for (int h = 0; h < 2; ++h) {
        f32x4 v0 = *(const f32x4*)(myrow + h * 32 + 8 * g);
        f32x4 v1 = *(const f32x4*)(myrow + h * 32 + 8 * g + 4);
        FragU f;
        f.u[0] = pkbf(v0[0], v0[1]); f.u[1] = pkbf(v0[2], v0[3]);
        f.u[2] = pkbf(v1[0], v1[1]); f.u[3] = pkbf(v1[2], v1[3]);
        *(bf16x8*)(proj + (size_t)(r0 + i15) * K + h * 32 + 8 * g) = f.v;
    }
}

// ---------- pass 2: main kernel ----------
__global__ __launch_bounds__(BLOCK, 4) void gcn_main(
    const int* __restrict__ w, const int* __restrict__ c, const int* __restrict__ neg,
    const short* __restrict__ nodeb, const short* __restrict__ nproj,
    const short* __restrict__ cproj, const short* __restrict__ cwb,
    float* __restrict__ out)
{
    __shared__ float qlds[WPB][16 * QS];
    const int tid = threadIdx.x;
    const int lane = tid & 63;
    const int wid = tid >> 6;
    const int i15 = lane & 15;
    const int g = lane >> 4;

    const int tile = blockIdx.x * WPB + wid;
    const int b0 = tile * TILE;
    const int bm = b0 + i15;

    // idx loads first
    const int iw = w[bm];
    const int ic = c[bm];
    int ing[NNEG];
#pragma unroll
    for (int j = 0; j < NNEG; ++j) ing[j] = neg[bm * NNEG + j];

    // node row gathers (A data for q GEMM)
    const short* wp = nodeb + (size_t)iw * D + g * 8;
    const short* cp = nodeb + (size_t)ic * D + g * 8;
    FragU wf[4], cf[4];
#pragma unroll
    for (int ks = 0; ks < 4; ++ks) {
        wf[ks].v = *(const bf16x8*)(wp + ks * 32);
        cf[ks].v = *(const bf16x8*)(cp + ks * 32);
    }

    // pf = bf16(we*ce); wf/cf die here
    FragU pf[4];
#pragma unroll
    for (int ks = 0; ks < 4; ++ks)
#pragma unroll
        for (int t = 0; t < 4; ++t) {
            float al = __uint_as_float(wf[ks].u[t] << 16);
            float ah = __uint_as_float(wf[ks].u[t] & 0xffff0000u);
            float bl = __uint_as_float(cf[ks].u[t] << 16);
            float bh = __uint_as_float(cf[ks].u[t] & 0xffff0000u);
            pf[ks].u[t] = pkbf(al * bl, ah * bh);
        }

    // projection row gathers — all in flight before/during the GEMM
    const short* prow = nproj + (size_t)iw * K;
    bf16x8 pr0 = *(const bf16x8*)(prow + 8 * g);
    bf16x8 pr1 = *(const bf16x8*)(prow + 32 + 8 * g);
    bf16x8 e0[1 + NNEG], e1[1 + NNEG];
#pragma unroll
    for (int j = 0; j < 1 + NNEG; ++j) {
        const int idx = (j == 0) ? ic : ing[j - 1];
        const short* er = cproj + (size_t)idx * K;
        e0[j] = *(const bf16x8*)(er + 8 * g);
        e1[j] = *(const bf16x8*)(er + 32 + 8 * g);
    }

    // q GEMM (cw fragments reloaded per ks from L1-hot cwb; not held)
    const f32x4 z4 = {0.f, 0.f, 0.f, 0.f};
    f32x4 Qa[4] = {z4, z4, z4, z4};
#pragma unroll
    for (int ks = 0; ks < 4; ++ks) {
        bf16x8 bk[4];
#pragma unroll
        for (int nb = 0; nb < 4; ++nb)
            bk[nb] = *(const bf16x8*)&cwb[(nb * 16 + i15) * D + ks * 32 + g * 8];
#pragma unroll
        for (int nb = 0; nb < 4; ++nb)
            Qa[nb] = __builtin_amdgcn_mfma_f32_16x16x32_bf16(pf[ks].v, bk[nb], Qa[nb], 0, 0, 0);
    }

    // redistribute q to pair-per-lane row layout via per-wave LDS (no barrier needed)
#pragma unroll
    for (int nb = 0; nb < 4; ++nb)
#pragma unroll
        for (int r = 0; r < 4; ++r)
            qlds[wid][(g * 4 + r) * QS + i15 + 16 * nb] = Qa[nb][r];
    const float* myrow = &qlds[wid][i15 * QS];
    f32x4 q0a = *(const f32x4*)(myrow + 8 * g);
    f32x4 q0b = *(const f32x4*)(myrow + 8 * g + 4);
    f32x4 q1a = *(const f32x4*)(myrow + 32 + 8 * g);
    f32x4 q1b = *(const f32x4*)(myrow + 32 + 8 * g + 4);
    float qv[16];
#pragma unroll
    for (int t = 0; t < 4; ++t) {
        qv[t] = q0a[t]; qv[4 + t] = q0b[t];
        qv[8 + t] = q1a[t]; qv[12 + t] = q1b[t];
    }

    // pos + negatives: s = q . proj_row  (cols split across g, reduce with 2 shuffles)
    float lossAcc = 0.f;
#pragma unroll
    for (int j = 0; j < 1 + NNEG; ++j) {
        float s = 0.f;
#pragma unroll
        for (int t = 0; t < 8; ++t) s += qv[t] * bf2f(e0[j][t]);
#pragma unroll
        for (int t = 0; t < 8; ++t) s += qv[8 + t] * bf2f(e1[j][t]);
        s += __shfl_xor(s, 16, 64);
        s += __shfl_xor(s, 32, 64);
        lossAcc += log_sigmoid(j == 0 ? s : -s);   // replicated x4 over g
    }

    // softmax(q) — row layout, coalesced float4 stores
    float* __restrict__ outq = out + 1;
    float* __restrict__ outp = out + 1 + (size_t)B_TOTAL * K;
    {
        float m = qv[0];
#pragma unroll
        for (int t = 1; t < 16; ++t) m = fmaxf(m, qv[t]);
        m = fmaxf(m, __shfl_xor(m, 16, 64));
        m = fmaxf(m, __shfl_xor(m, 32, 64));
        float ev[16], s = 0.f;
#pragma unroll
        for (int t = 0; t < 16; ++t) { ev[t] = __expf(qv[t] - m); s += ev[t]; }
        s += __shfl_xor(s, 16, 64);
        s += __shfl_xor(s, 32, 64);
        float inv = 1.f / s;
        float* orow = outq + (size_t)bm * K;
        float4 o;
        o = make_float4(ev[0] * inv, ev[1] * inv, ev[2] * inv, ev[3] * inv);
        *(float4*)(orow + 8 * g) = o;
        o = make_float4(ev[4] * inv, ev[5] * inv, ev[6] * inv, ev[7] * inv);
        *(float4*)(orow + 8 * g + 4) = o;
        o = make_float4(ev[8] * inv, ev[9] * inv, ev[10] * inv, ev[11] * inv);
        *(float4*)(orow + 32 + 8 * g) = o;
        o = make_float4(ev[12] * inv, ev[13] * inv, ev[14] * inv, ev[15] * inv);
        *(float4*)(orow + 32 + 8 * g + 4) = o;
    }
    // prior = softmax(NodeProj[w]) — gathered row
    {
        float pv[16];
#pragma unroll
        for (int t = 0; t < 8; ++t) { pv[t] = bf2f(pr0[t]); pv[8 + t] = bf2f(pr1[t]); }
        float m = pv[0];
#pragma unroll
        for (int t = 1; t < 16; ++t) m = fmaxf(m, pv[t]);
        m = fmaxf(m, __shfl_xor(m, 16, 64));
        m = fmaxf(m, __shfl_xor(m, 32, 64));
        float ev[16], s = 0.f;
#pragma unroll
        for (int t = 0; t < 16; ++t) { ev[t] = __expf(pv[t] - m); s += ev[t]; }
        s += __shfl_xor(s, 16, 64);
        s += __shfl_xor(s, 32, 64);
        float inv = 1.f / s;
        float* orow = outp + (size_t)bm * K;
        float4 o;
        o = make_float4(ev[0] * inv, ev[1] * inv, ev[2] * inv, ev[3] * inv);
        *(float4*)(orow + 8 * g) = o;
        o = make_float4(ev[4] * inv, ev[5] * inv, ev[6] * inv, ev[7] * inv);
        *(float4*)(orow + 8 * g + 4) = o;
        o = make_float4(ev[8] * inv, ev[9] * inv, ev[10] * inv, ev[11] * inv);
        *(float4*)(orow + 32 + 8 * g) = o;
        o = make_float4(ev[12] * inv, ev[13] * inv, ev[14] * inv, ev[15] * inv);
        *(float4*)(orow + 32 + 8 * g + 4) = o;
    }

    float tot = lossAcc;
#pragma unroll
    for (int msk = 1; msk < 64; msk <<= 1) tot += __shfl_xor(tot, msk, 64);
    if (lane == 0) atomicAdd(out, -tot / (4.f * (float)B_TOTAL));   // /4: g replication
}

// ---------------- fp32 fallback (R2 kernel, proven) ----------------
__global__ __launch_bounds__(BLOCK) void gcn_mfma_kernel(
    const int* __restrict__ w, const int* __restrict__ c, const int* __restrict__ neg,
    const float* __restrict__ node_emb, const float* __restrict__ ctx_emb,
    const float* __restrict__ comm_w, float* __restrict__ out)
{
    __shared__ __align__(16) short cw_lds[K * CWS];
    const int tid = threadIdx.x;
    const int lane = tid & 63;
    const int wid = tid >> 6;
    const int i15 = lane & 15;
    const int g = lane >> 4;

    for (int i = tid * 4; i < K * D; i += BLOCK * 4) {
        float4 v = *(const float4*)(comm_w + i);
        int row = i >> 7, col = i & 127;
        unsigned* dst = (unsigned*)&cw_lds[row * CWS + col];
        dst[0] = pkbf(v.x, v.y);
        dst[1] = pkbf(v.z, v.w);
    }
    __syncthreads();

    bf16x8 bfr[4][4];
#pragma unroll
    for (int ks = 0; ks < 4; ++ks)
#pragma unroll
        for (int nb = 0; nb < 4; ++nb)
            bfr[ks][nb] = *(const bf16x8*)&cw_lds[(nb * 16 + i15) * CWS + ks * 32 + g * 8];

    const int tile = blockIdx.x * WPB + wid;
    const int b0 = tile * TILE;
    const int bm = b0 + i15;
    const int iw = w[bm], ic = c[bm];
    int ing[NNEG];
#pragma unroll
    for (int j = 0; j < NNEG; ++j) ing[j] = neg[bm * NNEG + j];

    const f32x4 z4 = {0.f, 0.f, 0.f, 0.f};
    f32x4 Qa[4] = {z4, z4, z4, z4};
    f32x4 Pa[4] = {z4, z4, z4, z4};

#pragma unroll
    for (int ks = 0; ks < 4; ++ks) {
        const float* wp = node_emb + (size_t)iw * D + ks * 32 + g * 8;
        const float* cp = node_emb + (size_t)ic * D + ks * 32 + g * 8;
        float4 w0 = *(const float4*)wp, w1 = *(const float4*)(wp + 4);
        float4 c0 = *(const float4*)cp, c1 = *(const float4*)(cp + 4);
        FragU wf, pf;
        wf.u[0] = pkbf(w0.x, w0.y);               wf.u[1] = pkbf(w0.z, w0.w);
        wf.u[2] = pkbf(w1.x, w1.y);               wf.u[3] = pkbf(w1.z, w1.w);
        pf.u[0] = pkbf(w0.x * c0.x, w0.y * c0.y); pf.u[1] = pkbf(w0.z * c0.z, w0.w * c0.w);
        pf.u[2] = pkbf(w1.x * c1.x, w1.y * c1.y); pf.u[3] = pkbf(w1.z * c1.z, w1.w * c1.w);
#pragma unroll
        for (int nb = 0; nb < 4; ++nb) {
            Pa[nb] = __builtin_amdgcn_mfma_f32_16x16x32_bf16(wf.v, bfr[ks][nb], Pa[nb], 0, 0, 0);
            Qa[nb] = __builtin_amdgcn_mfma_f32_16x16x32_bf16(pf.v, bfr[ks][nb], Qa[nb], 0, 0, 0);
        }
    }

    float lossAcc = 0.f;
#pragma unroll
    for (int j = 0; j < 1 + NNEG; ++j) {
        const int idx = (j == 0) ? ic : ing[j - 1];
        const float* ebase = ctx_emb + (size_t)idx * D;
        f32x4 Fa[4] = {z4, z4, z4, z4};
#pragma unroll
        for (int ks = 0; ks < 4; ++ks) {
            const float* ep = ebase + ks * 32 + g * 8;
            float4 a0 = *(const float4*)ep, a1 = *(const float4*)(ep + 4);
            FragU ef;
            ef.u[0] = pkbf(a0.x, a0.y); ef.u[1] = pkbf(a0.z, a0.w);
            ef.u[2] = pkbf(a1.x, a1.y); ef.u[3] = pkbf(a1.z, a1.w);
#pragma unroll
            for (int nb = 0; nb < 4; ++nb)
                Fa[nb] = __builtin_amdgcn_mfma_f32_16x16x32_bf16(ef.v, bfr[ks][nb], Fa[nb], 0, 0, 0);
        }
#pragma unroll
        for (int r = 0; r < 4; ++r) {
            float s = Fa[0][r] * Qa[0][r] + Fa[1][r] * Qa[1][r] + Fa[2][r] * Qa[2][r] + Fa[3][r] * Qa[3][r];
            s += __shfl_xor(s, 1, 64);
            s += __shfl_xor(s, 2, 64);
            s += __shfl_xor(s, 4, 64);
            s += __shfl_xor(s, 8, 64);
            lossAcc += log_sigmoid(j == 0 ? s : -s);
        }
    }

    float* __restrict__ outq = out + 1;
    float* __restrict__ outp = out + 1 + (size_t)B_TOTAL * K;
#pragma unroll
    for (int r = 0; r < 4; ++r) {
        const size_t obase = (size_t)(b0 + g * 4 + r) * K + i15;
        {
            float m = fmaxf(fmaxf(Qa[0][r], Qa[1][r]), fmaxf(Qa[2][r], Qa[3][r]));
            m = fmaxf(m, __shfl_xor(m, 1, 64)); m = fmaxf(m, __shfl_xor(m, 2, 64));
            m = fmaxf(m, __shfl_xor(m, 4, 64)); m = fmaxf(m, __shfl_xor(m, 8, 64));
            float e0 = __expf(Qa[0][r] - m), e1 = __expf(Qa[1][r] - m);
            float e2 = __expf(Qa[2][r] - m), e3 = __expf(Qa[3][r] - m);
            float s = e0 + e1 + e2 + e3;
            s += __shfl_xor(s, 1, 64); s += __shfl_xor(s, 2, 64);
            s += __shfl_xor(s, 4, 64); s += __shfl_xor(s, 8, 64);
            float inv = 1.f / s;
            outq[obase]      = e0 * inv; outq[obase + 16] = e1 * inv;
            outq[obase + 32] = e2 * inv; outq[obase + 48] = e3 * inv;
        }
        {
            float m = fmaxf(fmaxf(Pa[0][r], Pa[1][r]), fmaxf(Pa[2][r], Pa[3][r]));
            m = fmaxf(m, __shfl_xor(m, 1, 64)); m = fmaxf(m, __shfl_xor(m, 2, 64));
            m = fmaxf(m, __shfl_xor(m, 4, 64)); m = fmaxf(m, __shfl_xor(m, 8, 64));
            float e0 = __expf(Pa[0][r] - m), e1 = __expf(Pa[1][r] - m);
            float e2 = __expf(Pa[2][r] - m), e3 = __expf(Pa[3][r] - m);
            float s = e0 + e1 + e2 + e3;
            s += __shfl_xor(s, 1, 64); s += __shfl_xor(s, 2, 64);
            s += __shfl_xor(s, 4, 64); s += __shfl_xor(s, 8, 64);
            float inv = 1.f / s;
            outp[obase]      = e0 * inv; outp[obase + 16] = e1 * inv;
            outp[obase + 32] = e2 * inv; outp[obase + 48] = e3 * inv;
        }
    }

    float tot = lossAcc;
#pragma unroll
    for (int msk = 1; msk < 64; msk <<= 1) tot += __shfl_xor(tot, msk, 64);
    if (lane == 0) atomicAdd(out, -tot / (16.f * (float)B_TOTAL));
}

extern "C" void kernel_launch(void* const* d_in, const int* in_sizes, int n_in,
                              void* d_out, int out_size, void* d_ws, size_t ws_size,
                              hipStream_t stream) {
    const int* w = (const int*)d_in[0];
    const int* c = (const int*)d_in[1];
    const int* neg = (const int*)d_in[2];
    // d_in[3] = temp (unused)
    const float* node_emb = (const float*)d_in[4];
    const float* ctx_emb = (const float*)d_in[5];
    const float* comm_w = (const float*)d_in[6];
    float* out = (float*)d_out;

    const size_t tbl_elems = (size_t)SIZE_N * D;    // 12.8M
    const size_t proj_elems = (size_t)SIZE_N * K;   // 6.4M
    const size_t need = (tbl_elems + 2 * proj_elems + (size_t)K * D) * sizeof(short);  // ~51.2 MB

    if (ws_size >= need) {
        short* nodeb = (short*)d_ws;
        short* nproj = nodeb + tbl_elems;
        short* cproj = nproj + proj_elems;
        short* cwb = cproj + proj_elems;
        precompute<<<GRID_PRE, BLOCK, 0, stream>>>(node_emb, ctx_emb, comm_w,
                                                   nodeb, nproj, cproj, cwb, out);
        gcn_main<<<GRID_MAIN, BLOCK, 0, stream>>>(w, c, neg, nodeb, nproj, cproj, cwb, out);
    } else {
        zero_loss<<<1, 64, 0, stream>>>(out);
        gcn_mfma_kernel<<<GRID_MAIN, BLOCK, 0, stream>>>(w, c, neg, node_emb, ctx_emb, comm_w, out);
    }
}